// Round 3
// baseline (235.348 us; speedup 1.0000x reference)
//
#include <hip/hip_runtime.h>

typedef _Float16 half_t;
typedef _Float16 h2 __attribute__((ext_vector_type(2)));

constexpr int Nc = 4, Cc = 256, Hc = 96, Wc = 160;
constexpr int RXc = 4, RYc = 4;
constexpr int WIN = 10;          // (2*RX+1)+1 integer grid per axis
constexpr int NPOS = WIN * WIN;  // 100
constexpr int Dc = 81;           // 9*9 displacements
constexpr int PIX = Hc * Wc;     // 15360
constexpr int NPIX = Nc * PIX;   // 61440

// Tiled transpose fp32->fp32: A[R][S] -> B[S][R] per batch (blockIdx.z)
__global__ __launch_bounds__(256) void transpose_rs(const float* __restrict__ in,
                                                    float* __restrict__ out,
                                                    int R, int S) {
    __shared__ float tile[32][33];
    size_t base = (size_t)blockIdx.z * (size_t)R * (size_t)S;
    const float* A = in + base;
    float* B = out + base;
    int s0 = blockIdx.x * 32;
    int r0 = blockIdx.y * 32;
    int tx = threadIdx.x, ty = threadIdx.y;
    #pragma unroll
    for (int i = ty; i < 32; i += 8) {
        int r = r0 + i, s = s0 + tx;
        if (r < R && s < S) tile[i][tx] = A[(size_t)r * S + s];
    }
    __syncthreads();
    #pragma unroll
    for (int i = ty; i < 32; i += 8) {
        int s = s0 + i, r = r0 + tx;
        if (s < S && r < R) B[(size_t)s * R + r] = tile[tx][i];
    }
}

// Tiled transpose + cast for BOTH features in one launch:
// z in [0, 2*Nc): batch = z>>1, src/dst pair = z&1.
// A[C][P] fp32 -> B[P][C] fp16, R=Cc (mult of 32), S=PIX (mult of 32).
__global__ __launch_bounds__(256) void transpose_cvt2(const float* __restrict__ in1,
                                                      const float* __restrict__ in2,
                                                      half_t* __restrict__ out1,
                                                      half_t* __restrict__ out2,
                                                      int R, int S) {
    __shared__ float tile[32][33];
    int b = blockIdx.z >> 1;
    int which = blockIdx.z & 1;
    const float* A = (which ? in2 : in1) + (size_t)b * R * S;
    half_t* B = (which ? out2 : out1) + (size_t)b * R * S;
    int s0 = blockIdx.x * 32;
    int r0 = blockIdx.y * 32;
    int tx = threadIdx.x, ty = threadIdx.y;
    #pragma unroll
    for (int i = ty; i < 32; i += 8) {
        int r = r0 + i, s = s0 + tx;
        tile[i][tx] = A[(size_t)r * S + s];
    }
    __syncthreads();
    #pragma unroll
    for (int i = ty; i < 32; i += 8) {
        int s = s0 + i;
        int rr = r0 + 2 * tx;
        if (tx < 16) {
            h2 v;
            v.x = (half_t)tile[2 * tx][i];
            v.y = (half_t)tile[2 * tx + 1][i];
            *(h2*)(B + (size_t)s * R + rr) = v;
        }
    }
}

// Main: one block per pixel. f1t/f2t are NHWC fp16. cv is [N,H,W,D] fp32.
// f1 fragment lives in registers (8 x float4 per lane); no LDS re-reads.
__global__ __launch_bounds__(256) void cv_main(const half_t* __restrict__ f1t,
                                               const half_t* __restrict__ f2t,
                                               const float* __restrict__ ofs,
                                               float* __restrict__ cv) {
    // XCD-aware swizzle: contiguous pixel chunk per XCD (NPIX % 8 == 0)
    int nwg = gridDim.x;
    int bid = blockIdx.x;
    int cpx = nwg >> 3;
    int pix = (bid & 7) * cpx + (bid >> 3);

    int n = pix / PIX;
    int hw = pix - n * PIX;
    int h = hw / Wc, w = hw - h * Wc;
    int tid = threadIdx.x;
    int lane = tid & 3;
    int group = tid >> 2;  // 0..63

    __shared__ float gs[NPOS];

    // Hoist this lane's f1 fragment into registers: slots it*4+lane, it=0..7.
    // (All groups read the same 512B -> L1 broadcast; trivial traffic.)
    const float4* f1g = (const float4*)(f1t + (size_t)pix * Cc);
    float4 f1r[8];
    #pragma unroll
    for (int it = 0; it < 8; ++it) f1r[it] = f1g[it * 4 + lane];

    float ofx = ofs[(size_t)(n * 2 + 0) * PIX + hw];
    float ofy = ofs[(size_t)(n * 2 + 1) * PIX + hw];
    float xc = (float)w + ofx;
    float yc = (float)h + ofy;
    float x0f = floorf(xc), y0f = floorf(yc);
    float wx = xc - x0f, wy = yc - y0f;
    int xi0 = (int)x0f - RXc;
    int yi0 = (int)y0f - RYc;

    #pragma unroll
    for (int pass = 0; pass < 2; ++pass) {
        int pos = pass * 64 + group;
        if (pos < NPOS) {
            int j = pos / WIN;
            int i = pos - j * WIN;
            int x = xi0 + i, y = yi0 + j;
            float g = 0.f;
            if (x >= 0 && x < Wc && y >= 0 && y < Hc) {
                const float4* f2v =
                    (const float4*)(f2t + ((size_t)(n * Hc + y) * Wc + x) * Cc);
                float acc0 = 0.f, acc1 = 0.f;
                #pragma unroll
                for (int it = 0; it < 8; ++it) {
                    float4 b = f2v[it * 4 + lane];  // 8 halves
                    h2* ah = (h2*)&f1r[it];
                    h2* bh = (h2*)&b;
                    acc0 = __builtin_amdgcn_fdot2(ah[0], bh[0], acc0, false);
                    acc1 = __builtin_amdgcn_fdot2(ah[1], bh[1], acc1, false);
                    acc0 = __builtin_amdgcn_fdot2(ah[2], bh[2], acc0, false);
                    acc1 = __builtin_amdgcn_fdot2(ah[3], bh[3], acc1, false);
                }
                g = acc0 + acc1;
            }
            g += __shfl_xor(g, 1);
            g += __shfl_xor(g, 2);
            if (lane == 0) gs[pos] = g;
        }
    }
    __syncthreads();

    if (tid < Dc) {
        int dyi = tid / 9, dxi = tid - dyi * 9;
        float g00 = gs[dyi * WIN + dxi];
        float g01 = gs[dyi * WIN + dxi + 1];
        float g10 = gs[(dyi + 1) * WIN + dxi];
        float g11 = gs[(dyi + 1) * WIN + dxi + 1];
        float v = (g00 * (1.f - wx) + g01 * wx) * (1.f - wy) +
                  (g10 * (1.f - wx) + g11 * wx) * wy;
        cv[(size_t)pix * Dc + tid] = v;
    }
}

// Fallback (workspace too small): direct NCHW fp32, uncoalesced but correct.
__global__ __launch_bounds__(128) void cv_naive(const float* __restrict__ f1,
                                                const float* __restrict__ f2,
                                                const float* __restrict__ ofs,
                                                float* __restrict__ out) {
    int pix = blockIdx.x;
    int n = pix / PIX;
    int hw = pix - n * PIX;
    int h = hw / Wc, w = hw - h * Wc;
    int tid = threadIdx.x;

    __shared__ float gs[NPOS];

    float ofx = ofs[(size_t)(n * 2 + 0) * PIX + hw];
    float ofy = ofs[(size_t)(n * 2 + 1) * PIX + hw];
    float xc = (float)w + ofx;
    float yc = (float)h + ofy;
    float x0f = floorf(xc), y0f = floorf(yc);
    float wx = xc - x0f, wy = yc - y0f;
    int xi0 = (int)x0f - RXc;
    int yi0 = (int)y0f - RYc;

    if (tid < NPOS) {
        int j = tid / WIN, i = tid - (tid / WIN) * WIN;
        int x = xi0 + i, y = yi0 + j;
        float g = 0.f;
        if (x >= 0 && x < Wc && y >= 0 && y < Hc) {
            const float* p1 = f1 + (size_t)n * Cc * PIX + hw;
            const float* p2 = f2 + (size_t)n * Cc * PIX + (size_t)y * Wc + x;
            for (int c = 0; c < Cc; ++c)
                g += p1[(size_t)c * PIX] * p2[(size_t)c * PIX];
        }
        gs[tid] = g;
    }
    __syncthreads();

    if (tid < Dc) {
        int dyi = tid / 9, dxi = tid - dyi * 9;
        float g00 = gs[dyi * WIN + dxi];
        float g01 = gs[dyi * WIN + dxi + 1];
        float g10 = gs[(dyi + 1) * WIN + dxi];
        float g11 = gs[(dyi + 1) * WIN + dxi + 1];
        float v = (g00 * (1.f - wx) + g01 * wx) * (1.f - wy) +
                  (g10 * (1.f - wx) + g11 * wx) * wy;
        out[(size_t)(n * Dc + tid) * PIX + hw] = v;
    }
}

extern "C" void kernel_launch(void* const* d_in, const int* in_sizes, int n_in,
                              void* d_out, int out_size, void* d_ws, size_t ws_size,
                              hipStream_t stream) {
    const float* f1 = (const float*)d_in[0];
    const float* f2 = (const float*)d_in[1];
    const float* ofs = (const float*)d_in[2];
    float* out = (float*)d_out;

    size_t feat_elems = (size_t)Nc * Cc * PIX;  // 15,728,640
    size_t cv_elems = (size_t)NPIX * Dc;        // 4,976,640
    // fp16 f1t + fp16 f2t + fp32 cvt
    size_t need = 2 * feat_elems * sizeof(half_t) + cv_elems * sizeof(float);

    if (ws_size >= need) {
        half_t* f1t = (half_t*)d_ws;
        half_t* f2t = f1t + feat_elems;
        float* cvt = (float*)(f2t + feat_elems);
        dim3 tb(32, 8);
        // NCHW -> NHWC fp16 for both f1 and f2 in one launch
        transpose_cvt2<<<dim3(PIX / 32, Cc / 32, 2 * Nc), tb, 0, stream>>>(
            f1, f2, f1t, f2t, Cc, PIX);
        cv_main<<<NPIX, 256, 0, stream>>>(f1t, f2t, ofs, cvt);
        // [P][D] -> [D][P] fp32
        transpose_rs<<<dim3((Dc + 31) / 32, PIX / 32, Nc), tb, 0, stream>>>(cvt, out, PIX, Dc);
    } else {
        cv_naive<<<NPIX, 128, 0, stream>>>(f1, f2, ofs, out);
    }
}

// Round 4
// 155.613 us; speedup vs baseline: 1.5124x; 1.5124x over previous
//
#include <hip/hip_runtime.h>

typedef _Float16 half_t;
typedef _Float16 h2 __attribute__((ext_vector_type(2)));

constexpr int Nc = 4, Cc = 256, Hc = 96, Wc = 160;
constexpr int RXc = 4, RYc = 4;
constexpr int WIN = 10;          // (2*RX+1)+1 integer grid per axis
constexpr int NPOS = WIN * WIN;  // 100
constexpr int Dc = 81;           // 9*9 displacements
constexpr int PIX = Hc * Wc;     // 15360
constexpr int NPIX = Nc * PIX;   // 61440

// Tiled transpose fp32->fp32: A[R][S] -> B[S][R] per batch (blockIdx.z)
__global__ __launch_bounds__(256) void transpose_rs(const float* __restrict__ in,
                                                    float* __restrict__ out,
                                                    int R, int S) {
    __shared__ float tile[32][33];
    size_t base = (size_t)blockIdx.z * (size_t)R * (size_t)S;
    const float* A = in + base;
    float* B = out + base;
    int s0 = blockIdx.x * 32;
    int r0 = blockIdx.y * 32;
    int tx = threadIdx.x, ty = threadIdx.y;
    #pragma unroll
    for (int i = ty; i < 32; i += 8) {
        int r = r0 + i, s = s0 + tx;
        if (r < R && s < S) tile[i][tx] = A[(size_t)r * S + s];
    }
    __syncthreads();
    #pragma unroll
    for (int i = ty; i < 32; i += 8) {
        int s = s0 + i, r = r0 + tx;
        if (s < S && r < R) B[(size_t)s * R + r] = tile[tx][i];
    }
}

// Tiled transpose + cast for BOTH features in one launch:
// z in [0, 2*Nc): batch = z>>1, src/dst pair = z&1.
// A[C][P] fp32 -> B[P][C] fp16, R=Cc (mult of 32), S=PIX (mult of 32).
__global__ __launch_bounds__(256) void transpose_cvt2(const float* __restrict__ in1,
                                                      const float* __restrict__ in2,
                                                      half_t* __restrict__ out1,
                                                      half_t* __restrict__ out2,
                                                      int R, int S) {
    __shared__ float tile[32][33];
    int b = blockIdx.z >> 1;
    int which = blockIdx.z & 1;
    const float* A = (which ? in2 : in1) + (size_t)b * R * S;
    half_t* B = (which ? out2 : out1) + (size_t)b * R * S;
    int s0 = blockIdx.x * 32;
    int r0 = blockIdx.y * 32;
    int tx = threadIdx.x, ty = threadIdx.y;
    #pragma unroll
    for (int i = ty; i < 32; i += 8) {
        int r = r0 + i, s = s0 + tx;
        tile[i][tx] = A[(size_t)r * S + s];
    }
    __syncthreads();
    #pragma unroll
    for (int i = ty; i < 32; i += 8) {
        int s = s0 + i;
        int rr = r0 + 2 * tx;
        if (tx < 16) {
            h2 v;
            v.x = (half_t)tile[2 * tx][i];
            v.y = (half_t)tile[2 * tx + 1][i];
            *(h2*)(B + (size_t)s * R + rr) = v;
        }
    }
}

// Main: one block per pixel. f1t/f2t are NHWC fp16. cv is [N,H,W,D] fp32.
// 8-lane groups: each gather instruction fetches one full 128B L2 line.
__global__ __launch_bounds__(256) void cv_main(const half_t* __restrict__ f1t,
                                               const half_t* __restrict__ f2t,
                                               const float* __restrict__ ofs,
                                               float* __restrict__ cv) {
    // XCD-aware swizzle: contiguous pixel chunk per XCD (NPIX % 8 == 0)
    int nwg = gridDim.x;
    int bid = blockIdx.x;
    int cpx = nwg >> 3;
    int pix = (bid & 7) * cpx + (bid >> 3);

    int n = pix / PIX;
    int hw = pix - n * PIX;
    int h = hw / Wc, w = hw - h * Wc;
    int tid = threadIdx.x;
    int lane = tid & 7;   // 8 lanes per position -> 128B contiguous per instr
    int group = tid >> 3; // 0..31

    __shared__ half_t f1s[Cc];  // 512 B
    __shared__ float gs[NPOS];

    // Stage f1 vector (512B) cooperatively, coalesced.
    if (tid < Cc / 8)
        ((float4*)f1s)[tid] = ((const float4*)(f1t + (size_t)pix * Cc))[tid];

    float ofx = ofs[(size_t)(n * 2 + 0) * PIX + hw];
    float ofy = ofs[(size_t)(n * 2 + 1) * PIX + hw];
    float xc = (float)w + ofx;
    float yc = (float)h + ofy;
    float x0f = floorf(xc), y0f = floorf(yc);
    float wx = xc - x0f, wy = yc - y0f;
    int xi0 = (int)x0f - RXc;
    int yi0 = (int)y0f - RYc;

    __syncthreads();

    // This lane's f1 fragment: chunk c covers bytes [c*128, c*128+128);
    // lane owns float4 slot `lane` within each chunk. Loop-invariant ->
    // read from LDS ONCE (4 ds_read_b128), reuse across all 4 passes.
    const float4* f1v = (const float4*)f1s;
    float4 f1r[4];
    #pragma unroll
    for (int c = 0; c < 4; ++c) f1r[c] = f1v[c * 8 + lane];

    #pragma unroll
    for (int pass = 0; pass < 4; ++pass) {
        int pos = pass * 32 + group;
        if (pos < NPOS) {
            int j = pos / WIN;
            int i = pos - j * WIN;
            int x = xi0 + i, y = yi0 + j;
            float g = 0.f;
            if (x >= 0 && x < Wc && y >= 0 && y < Hc) {
                const float4* f2v =
                    (const float4*)(f2t + ((size_t)(n * Hc + y) * Wc + x) * Cc);
                float acc0 = 0.f, acc1 = 0.f;
                #pragma unroll
                for (int c = 0; c < 4; ++c) {
                    float4 b = f2v[c * 8 + lane];  // 8 halves, 1/8 of a line
                    h2* ah = (h2*)&f1r[c];
                    h2* bh = (h2*)&b;
                    acc0 = __builtin_amdgcn_fdot2(ah[0], bh[0], acc0, false);
                    acc1 = __builtin_amdgcn_fdot2(ah[1], bh[1], acc1, false);
                    acc0 = __builtin_amdgcn_fdot2(ah[2], bh[2], acc0, false);
                    acc1 = __builtin_amdgcn_fdot2(ah[3], bh[3], acc1, false);
                }
                g = acc0 + acc1;
            }
            g += __shfl_xor(g, 1);
            g += __shfl_xor(g, 2);
            g += __shfl_xor(g, 4);
            if (lane == 0) gs[pos] = g;
        }
    }
    __syncthreads();

    if (tid < Dc) {
        int dyi = tid / 9, dxi = tid - dyi * 9;
        float g00 = gs[dyi * WIN + dxi];
        float g01 = gs[dyi * WIN + dxi + 1];
        float g10 = gs[(dyi + 1) * WIN + dxi];
        float g11 = gs[(dyi + 1) * WIN + dxi + 1];
        float v = (g00 * (1.f - wx) + g01 * wx) * (1.f - wy) +
                  (g10 * (1.f - wx) + g11 * wx) * wy;
        cv[(size_t)pix * Dc + tid] = v;
    }
}

// Fallback (workspace too small): direct NCHW fp32, uncoalesced but correct.
__global__ __launch_bounds__(128) void cv_naive(const float* __restrict__ f1,
                                                const float* __restrict__ f2,
                                                const float* __restrict__ ofs,
                                                float* __restrict__ out) {
    int pix = blockIdx.x;
    int n = pix / PIX;
    int hw = pix - n * PIX;
    int h = hw / Wc, w = hw - h * Wc;
    int tid = threadIdx.x;

    __shared__ float gs[NPOS];

    float ofx = ofs[(size_t)(n * 2 + 0) * PIX + hw];
    float ofy = ofs[(size_t)(n * 2 + 1) * PIX + hw];
    float xc = (float)w + ofx;
    float yc = (float)h + ofy;
    float x0f = floorf(xc), y0f = floorf(yc);
    float wx = xc - x0f, wy = yc - y0f;
    int xi0 = (int)x0f - RXc;
    int yi0 = (int)y0f - RYc;

    if (tid < NPOS) {
        int j = tid / WIN, i = tid - (tid / WIN) * WIN;
        int x = xi0 + i, y = yi0 + j;
        float g = 0.f;
        if (x >= 0 && x < Wc && y >= 0 && y < Hc) {
            const float* p1 = f1 + (size_t)n * Cc * PIX + hw;
            const float* p2 = f2 + (size_t)n * Cc * PIX + (size_t)y * Wc + x;
            for (int c = 0; c < Cc; ++c)
                g += p1[(size_t)c * PIX] * p2[(size_t)c * PIX];
        }
        gs[tid] = g;
    }
    __syncthreads();

    if (tid < Dc) {
        int dyi = tid / 9, dxi = tid - dyi * 9;
        float g00 = gs[dyi * WIN + dxi];
        float g01 = gs[dyi * WIN + dxi + 1];
        float g10 = gs[(dyi + 1) * WIN + dxi];
        float g11 = gs[(dyi + 1) * WIN + dxi + 1];
        float v = (g00 * (1.f - wx) + g01 * wx) * (1.f - wy) +
                  (g10 * (1.f - wx) + g11 * wx) * wy;
        out[(size_t)(n * Dc + tid) * PIX + hw] = v;
    }
}

extern "C" void kernel_launch(void* const* d_in, const int* in_sizes, int n_in,
                              void* d_out, int out_size, void* d_ws, size_t ws_size,
                              hipStream_t stream) {
    const float* f1 = (const float*)d_in[0];
    const float* f2 = (const float*)d_in[1];
    const float* ofs = (const float*)d_in[2];
    float* out = (float*)d_out;

    size_t feat_elems = (size_t)Nc * Cc * PIX;  // 15,728,640
    size_t cv_elems = (size_t)NPIX * Dc;        // 4,976,640
    // fp16 f1t + fp16 f2t + fp32 cvt
    size_t need = 2 * feat_elems * sizeof(half_t) + cv_elems * sizeof(float);

    if (ws_size >= need) {
        half_t* f1t = (half_t*)d_ws;
        half_t* f2t = f1t + feat_elems;
        float* cvt = (float*)(f2t + feat_elems);
        dim3 tb(32, 8);
        // NCHW -> NHWC fp16 for both f1 and f2 in one launch
        transpose_cvt2<<<dim3(PIX / 32, Cc / 32, 2 * Nc), tb, 0, stream>>>(
            f1, f2, f1t, f2t, Cc, PIX);
        cv_main<<<NPIX, 256, 0, stream>>>(f1t, f2t, ofs, cvt);
        // [P][D] -> [D][P] fp32
        transpose_rs<<<dim3((Dc + 31) / 32, PIX / 32, Nc), tb, 0, stream>>>(cvt, out, PIX, Dc);
    } else {
        cv_naive<<<NPIX, 128, 0, stream>>>(f1, f2, ofs, out);
    }
}

// Round 5
// 152.939 us; speedup vs baseline: 1.5388x; 1.0175x over previous
//
#include <hip/hip_runtime.h>

typedef _Float16 half_t;
typedef _Float16 h2 __attribute__((ext_vector_type(2)));

constexpr int Nc = 4, Cc = 256, Hc = 96, Wc = 160;
constexpr int RXc = 4, RYc = 4;
constexpr int WIN = 10;          // (2*RX+1)+1 integer grid per axis
constexpr int NPOS = WIN * WIN;  // 100
constexpr int Dc = 81;           // 9*9 displacements
constexpr int PIX = Hc * Wc;     // 15360
constexpr int NPIX = Nc * PIX;   // 61440

// Tiled transpose fp32->fp32: A[R][S] -> B[S][R] per batch (blockIdx.z)
__global__ __launch_bounds__(256) void transpose_rs(const float* __restrict__ in,
                                                    float* __restrict__ out,
                                                    int R, int S) {
    __shared__ float tile[32][33];
    size_t base = (size_t)blockIdx.z * (size_t)R * (size_t)S;
    const float* A = in + base;
    float* B = out + base;
    int s0 = blockIdx.x * 32;
    int r0 = blockIdx.y * 32;
    int tx = threadIdx.x, ty = threadIdx.y;
    #pragma unroll
    for (int i = ty; i < 32; i += 8) {
        int r = r0 + i, s = s0 + tx;
        if (r < R && s < S) tile[i][tx] = A[(size_t)r * S + s];
    }
    __syncthreads();
    #pragma unroll
    for (int i = ty; i < 32; i += 8) {
        int s = s0 + i, r = r0 + tx;
        if (s < S && r < R) B[(size_t)s * R + r] = tile[tx][i];
    }
}

// Tiled transpose + cast for BOTH features in one launch:
// z in [0, 2*Nc): batch = z>>1, src/dst pair = z&1.
// A[C][P] fp32 -> B[P][C] fp16, R=Cc (mult of 32), S=PIX (mult of 32).
__global__ __launch_bounds__(256) void transpose_cvt2(const float* __restrict__ in1,
                                                      const float* __restrict__ in2,
                                                      half_t* __restrict__ out1,
                                                      half_t* __restrict__ out2,
                                                      int R, int S) {
    __shared__ float tile[32][33];
    int b = blockIdx.z >> 1;
    int which = blockIdx.z & 1;
    const float* A = (which ? in2 : in1) + (size_t)b * R * S;
    half_t* B = (which ? out2 : out1) + (size_t)b * R * S;
    int s0 = blockIdx.x * 32;
    int r0 = blockIdx.y * 32;
    int tx = threadIdx.x, ty = threadIdx.y;
    #pragma unroll
    for (int i = ty; i < 32; i += 8) {
        int r = r0 + i, s = s0 + tx;
        tile[i][tx] = A[(size_t)r * S + s];
    }
    __syncthreads();
    #pragma unroll
    for (int i = ty; i < 32; i += 8) {
        int s = s0 + i;
        int rr = r0 + 2 * tx;
        if (tx < 16) {
            h2 v;
            v.x = (half_t)tile[2 * tx][i];
            v.y = (half_t)tile[2 * tx + 1][i];
            *(h2*)(B + (size_t)s * R + rr) = v;
        }
    }
}

// Main: one block per pixel. f1t/f2t are NHWC fp16. cv is [N,H,W,D] fp32.
// 8-lane groups, full 128B line per gather instr; position byte-offsets
// precomputed once into LDS (block-uniform across passes).
__global__ __launch_bounds__(256) void cv_main(const half_t* __restrict__ f1t,
                                               const half_t* __restrict__ f2t,
                                               const float* __restrict__ ofs,
                                               float* __restrict__ cv) {
    // XCD-aware swizzle: contiguous pixel chunk per XCD (NPIX % 8 == 0)
    int nwg = gridDim.x;
    int bid = blockIdx.x;
    int cpx = nwg >> 3;
    int pix = (bid & 7) * cpx + (bid >> 3);

    int n = pix / PIX;
    int hw = pix - n * PIX;
    int h = hw / Wc, w = hw - h * Wc;
    int tid = threadIdx.x;
    int lane = tid & 7;   // 8 lanes per position -> 128B contiguous per instr
    int group = tid >> 3; // 0..31

    __shared__ half_t f1s[Cc];  // 512 B
    __shared__ float gs[NPOS];
    __shared__ int poff[NPOS];  // byte offset in f2t batch plane, or -1 if OOB

    // Stage f1 vector (512B) cooperatively, coalesced.
    if (tid < Cc / 8)
        ((float4*)f1s)[tid] = ((const float4*)(f1t + (size_t)pix * Cc))[tid];

    float ofx = ofs[(size_t)(n * 2 + 0) * PIX + hw];
    float ofy = ofs[(size_t)(n * 2 + 1) * PIX + hw];
    float xc = (float)w + ofx;
    float yc = (float)h + ofy;
    float x0f = floorf(xc), y0f = floorf(yc);
    float wx = xc - x0f, wy = yc - y0f;
    int xi0 = (int)x0f - RXc;
    int yi0 = (int)y0f - RYc;

    // Precompute the 100 gather offsets once (block-uniform values).
    if (tid < NPOS) {
        int j = tid / WIN;
        int i = tid - j * WIN;
        int x = xi0 + i, y = yi0 + j;
        bool valid = (x >= 0) & (x < Wc) & (y >= 0) & (y < Hc);
        poff[tid] = valid ? (int)(((unsigned)(y * Wc + x)) * (Cc * sizeof(half_t))) : -1;
    }
    __syncthreads();

    // This lane's f1 fragment: loop-invariant -> read from LDS ONCE.
    const float4* f1v = (const float4*)f1s;
    float4 f1r[4];
    #pragma unroll
    for (int c = 0; c < 4; ++c) f1r[c] = f1v[c * 8 + lane];

    const char* f2n = (const char*)(f2t + (size_t)n * (Hc * Wc) * Cc);

    #pragma unroll
    for (int pass = 0; pass < 4; ++pass) {
        int pos = pass * 32 + group;
        int off = (pos < NPOS) ? poff[pos] : -1;  // broadcast ds_read
        float g = 0.f;
        if (off >= 0) {
            const float4* f2v = (const float4*)(f2n + off);
            float acc0 = 0.f, acc1 = 0.f;
            #pragma unroll
            for (int c = 0; c < 4; ++c) {
                float4 b = f2v[c * 8 + lane];  // 16B of the position's 128B chunk
                h2* ah = (h2*)&f1r[c];
                h2* bh = (h2*)&b;
                acc0 = __builtin_amdgcn_fdot2(ah[0], bh[0], acc0, false);
                acc1 = __builtin_amdgcn_fdot2(ah[1], bh[1], acc1, false);
                acc0 = __builtin_amdgcn_fdot2(ah[2], bh[2], acc0, false);
                acc1 = __builtin_amdgcn_fdot2(ah[3], bh[3], acc1, false);
            }
            g = acc0 + acc1;
        }
        if (pos < NPOS) {
            g += __shfl_xor(g, 1);
            g += __shfl_xor(g, 2);
            g += __shfl_xor(g, 4);
            if (lane == 0) gs[pos] = g;
        }
    }
    __syncthreads();

    if (tid < Dc) {
        int dyi = tid / 9, dxi = tid - dyi * 9;
        float g00 = gs[dyi * WIN + dxi];
        float g01 = gs[dyi * WIN + dxi + 1];
        float g10 = gs[(dyi + 1) * WIN + dxi];
        float g11 = gs[(dyi + 1) * WIN + dxi + 1];
        float v = (g00 * (1.f - wx) + g01 * wx) * (1.f - wy) +
                  (g10 * (1.f - wx) + g11 * wx) * wy;
        cv[(size_t)pix * Dc + tid] = v;
    }
}

// Fallback (workspace too small): direct NCHW fp32, uncoalesced but correct.
__global__ __launch_bounds__(128) void cv_naive(const float* __restrict__ f1,
                                                const float* __restrict__ f2,
                                                const float* __restrict__ ofs,
                                                float* __restrict__ out) {
    int pix = blockIdx.x;
    int n = pix / PIX;
    int hw = pix - n * PIX;
    int h = hw / Wc, w = hw - h * Wc;
    int tid = threadIdx.x;

    __shared__ float gs[NPOS];

    float ofx = ofs[(size_t)(n * 2 + 0) * PIX + hw];
    float ofy = ofs[(size_t)(n * 2 + 1) * PIX + hw];
    float xc = (float)w + ofx;
    float yc = (float)h + ofy;
    float x0f = floorf(xc), y0f = floorf(yc);
    float wx = xc - x0f, wy = yc - y0f;
    int xi0 = (int)x0f - RXc;
    int yi0 = (int)y0f - RYc;

    if (tid < NPOS) {
        int j = tid / WIN, i = tid - (tid / WIN) * WIN;
        int x = xi0 + i, y = yi0 + j;
        float g = 0.f;
        if (x >= 0 && x < Wc && y >= 0 && y < Hc) {
            const float* p1 = f1 + (size_t)n * Cc * PIX + hw;
            const float* p2 = f2 + (size_t)n * Cc * PIX + (size_t)y * Wc + x;
            for (int c = 0; c < Cc; ++c)
                g += p1[(size_t)c * PIX] * p2[(size_t)c * PIX];
        }
        gs[tid] = g;
    }
    __syncthreads();

    if (tid < Dc) {
        int dyi = tid / 9, dxi = tid - dyi * 9;
        float g00 = gs[dyi * WIN + dxi];
        float g01 = gs[dyi * WIN + dxi + 1];
        float g10 = gs[(dyi + 1) * WIN + dxi];
        float g11 = gs[(dyi + 1) * WIN + dxi + 1];
        float v = (g00 * (1.f - wx) + g01 * wx) * (1.f - wy) +
                  (g10 * (1.f - wx) + g11 * wx) * wy;
        out[(size_t)(n * Dc + tid) * PIX + hw] = v;
    }
}

extern "C" void kernel_launch(void* const* d_in, const int* in_sizes, int n_in,
                              void* d_out, int out_size, void* d_ws, size_t ws_size,
                              hipStream_t stream) {
    const float* f1 = (const float*)d_in[0];
    const float* f2 = (const float*)d_in[1];
    const float* ofs = (const float*)d_in[2];
    float* out = (float*)d_out;

    size_t feat_elems = (size_t)Nc * Cc * PIX;  // 15,728,640
    size_t cv_elems = (size_t)NPIX * Dc;        // 4,976,640
    // fp16 f1t + fp16 f2t + fp32 cvt
    size_t need = 2 * feat_elems * sizeof(half_t) + cv_elems * sizeof(float);

    if (ws_size >= need) {
        half_t* f1t = (half_t*)d_ws;
        half_t* f2t = f1t + feat_elems;
        float* cvt = (float*)(f2t + feat_elems);
        dim3 tb(32, 8);
        // NCHW -> NHWC fp16 for both f1 and f2 in one launch
        transpose_cvt2<<<dim3(PIX / 32, Cc / 32, 2 * Nc), tb, 0, stream>>>(
            f1, f2, f1t, f2t, Cc, PIX);
        cv_main<<<NPIX, 256, 0, stream>>>(f1t, f2t, ofs, cvt);
        // [P][D] -> [D][P] fp32
        transpose_rs<<<dim3((Dc + 31) / 32, PIX / 32, Nc), tb, 0, stream>>>(cvt, out, PIX, Dc);
    } else {
        cv_naive<<<NPIX, 128, 0, stream>>>(f1, f2, ofs, out);
    }
}